// Round 1
// baseline (2213.382 us; speedup 1.0000x reference)
//
#include <hip/hip_runtime.h>

#define D 128
#define TWO_D 256
#define LDSR 264   // LDS row stride in bf16 units: 256 + 8 pad

typedef __attribute__((ext_vector_type(4))) float f32x4;
typedef __attribute__((ext_vector_type(8))) short bf16x8;

static __device__ __forceinline__ unsigned short f2bf(float x) {
  union { float f; unsigned u; } v; v.f = x;
  unsigned r = (v.u + 0x7fffu + ((v.u >> 16) & 1u)) >> 16;  // RNE
  return (unsigned short)r;
}

// Software grid barrier. Requires all blocks co-resident (grid sized via
// occupancy API in kernel_launch). Agent-scope acq_rel atomics provide the
// cross-XCD L2 writeback/invalidate. Timeout failsafe: a residency
// miscalculation produces a wrong answer, not a hang.
static __device__ __forceinline__ void gbar(int* bar, int target) {
  __syncthreads();   // compiler drains vmcnt/lgkmcnt before s_barrier
  if (threadIdx.x == 0) {
    __hip_atomic_fetch_add(bar, 1, __ATOMIC_ACQ_REL, __HIP_MEMORY_SCOPE_AGENT);
    long long t0 = clock64();
    while (__hip_atomic_load(bar, __ATOMIC_ACQUIRE, __HIP_MEMORY_SCOPE_AGENT) < target) {
      __builtin_amdgcn_s_sleep(2);
      if ((clock64() - t0) > 400000000LL) break;  // failsafe
    }
  }
  __syncthreads();
}

__global__ __launch_bounds__(256, 4) void gcn_fused(
    const float* __restrict__ nfeats, const float* __restrict__ efeats,
    const float* __restrict__ wmsg, const float* __restrict__ b1,
    const float* __restrict__ wapp, const float* __restrict__ b2,
    const int* __restrict__ src, const int* __restrict__ dst,
    unsigned short* __restrict__ X1, unsigned short* __restrict__ Wp,
    int* __restrict__ d_counts, int* __restrict__ offsets,
    int* __restrict__ rank, int2* __restrict__ edge_list,
    int* __restrict__ bar,
    float* __restrict__ out, int n_nodes, int n_edges) {
  __shared__ unsigned short xt[64 * LDSR];
  __shared__ int cnts[64];
  __shared__ int sc[256];

  const int tid = threadIdx.x;
  const int bid = blockIdx.x;
  const int GS = gridDim.x;          // blocks (all co-resident)
  const int nthr = GS * 256;
  const int gtid = bid * 256 + tid;

  // ---- P0: pack both weights into MFMA-B-fragment order; zero counts ----
  for (int p = gtid; p < 65536; p += nthr) {
    int j = p & 7;
    int lane = (p >> 3) & 63;
    int ot = (p >> 9) & 7;
    int k0i = (p >> 12) & 7;
    int g = p >> 15;
    int o = ot * 16 + (lane & 15);
    int k = k0i * 32 + (lane >> 4) * 8 + j;
    const float* W = g ? wapp : wmsg;
    Wp[p] = f2bf(W[o * 256 + k]);
  }
  for (int p = gtid; p < n_nodes; p += nthr) d_counts[p] = 0;
  gbar(bar, GS);

  // ---- P1: histogram + rank ----
  for (int e = gtid; e < n_edges; e += nthr)
    rank[e] = atomicAdd(&d_counts[dst[e]], 1);
  gbar(bar, 2 * GS);

  // ---- P2: exclusive scan of counts -> offsets (block 0 only) ----
  if (bid == 0) {
    const int C = (n_nodes + 255) / 256;   // 196
    int lo = tid * C, hi = lo + C;
    if (lo > n_nodes) lo = n_nodes;
    if (hi > n_nodes) hi = n_nodes;
    int s = 0;
    for (int i = lo; i < hi; ++i) s += d_counts[i];
    sc[tid] = s;
    __syncthreads();
    for (int off = 1; off < 256; off <<= 1) {
      int v = (tid >= off) ? sc[tid - off] : 0;
      __syncthreads();
      sc[tid] += v;
      __syncthreads();
    }
    int base = (tid > 0) ? sc[tid - 1] : 0;
    for (int i = lo; i < hi; ++i) { int c = d_counts[i]; offsets[i] = base; base += c; }
    if (tid == 0) offsets[n_nodes] = n_edges;
  }
  gbar(bar, 3 * GS);

  // ---- P3: scatter (atomic-free): edge_list[offsets[d]+rank[e]] = (e,src) ----
  for (int e = gtid; e < n_edges; e += nthr) {
    int d2 = dst[e];
    edge_list[offsets[d2] + rank[e]] = make_int2(e, src[e]);
  }
  gbar(bar, 4 * GS);

  // ---- P4: gather — one wave per node, software-pipelined (unchanged body) ----
  {
    const int lane = tid & 63;
    const int nwaves = nthr >> 6;
    const f32x4* nf4 = (const f32x4*)nfeats;
    const f32x4* ef4 = (const f32x4*)efeats;
    const int c32 = lane & 31;
    const int slot = lane >> 5;
    for (int w = (gtid >> 6); w < n_nodes; w += nwaves) {
      int beg = offsets[w], end = offsets[w + 1];
      int cnt = end - beg;
      f32x4 accn = (f32x4){0.f, 0.f, 0.f, 0.f};
      f32x4 acce = (f32x4){0.f, 0.f, 0.f, 0.f};
      for (int j0 = beg; j0 < end; j0 += 64) {
        int njj = end - j0; if (njj > 64) njj = 64;
        int e = 0, s = 0;
        if (lane < njj) { int2 es = edge_list[j0 + lane]; e = es.x; s = es.y; }
        int i0 = slot, i1 = 2 + slot;
        int ee0 = __shfl(e, i0), ss0 = __shfl(s, i0);
        int ee1 = __shfl(e, i1), ss1 = __shfl(s, i1);
        bool v0 = i0 < njj, v1 = i1 < njj;
        f32x4 a0 = (f32x4){0.f,0.f,0.f,0.f}, b0 = a0, a1 = a0, b1v = a0;
        if (v0) { a0 = nf4[(size_t)ss0 * 32 + c32];
                  b0 = __builtin_nontemporal_load(&ef4[(size_t)ee0 * 32 + c32]); }
        if (v1) { a1 = nf4[(size_t)ss1 * 32 + c32];
                  b1v = __builtin_nontemporal_load(&ef4[(size_t)ee1 * 32 + c32]); }
        for (int p = 0; p < njj; p += 4) {
          int n0 = (p + 4 + slot) & 63, n1 = (p + 6 + slot) & 63;
          int eeN0 = __shfl(e, n0), ssN0 = __shfl(s, n0);
          int eeN1 = __shfl(e, n1), ssN1 = __shfl(s, n1);
          bool u0 = p + 4 + slot < njj, u1 = p + 6 + slot < njj;
          f32x4 aN0 = (f32x4){0.f,0.f,0.f,0.f}, bN0 = aN0, aN1 = aN0, bN1 = aN0;
          if (u0) { aN0 = nf4[(size_t)ssN0 * 32 + c32];
                    bN0 = __builtin_nontemporal_load(&ef4[(size_t)eeN0 * 32 + c32]); }
          if (u1) { aN1 = nf4[(size_t)ssN1 * 32 + c32];
                    bN1 = __builtin_nontemporal_load(&ef4[(size_t)eeN1 * 32 + c32]); }
          if (v0) { accn += a0; acce += b0; }
          if (v1) { accn += a1; acce += b1v; }
          a0 = aN0; b0 = bN0; a1 = aN1; b1v = bN1; v0 = u0; v1 = u1;
        }
      }
      #pragma unroll
      for (int k = 0; k < 4; ++k) {
        accn[k] += __shfl_xor(accn[k], 32);
        acce[k] += __shfl_xor(acce[k], 32);
      }
      float inv = (cnt > 0) ? 1.0f / (float)cnt : 0.0f;
      f32x4 vv = (lane < 32) ? accn : acce;
      ushort4 o4;
      o4.x = f2bf(vv[0] * inv); o4.y = f2bf(vv[1] * inv);
      o4.z = f2bf(vv[2] * inv); o4.w = f2bf(vv[3] * inv);
      ((ushort4*)(X1 + (size_t)w * TWO_D))[lane] = o4;
    }
  }
  gbar(bar, 5 * GS);

  // ---- P5: node GEMMs (unchanged body, grid-stride over 64-node tiles) ----
  const int nblk = (n_nodes + 63) / 64;
  for (int blk = bid; blk < nblk; blk += GS) {
    const int base = blk * 64;
    if (tid < 64) {
      int g = base + tid;
      cnts[tid] = (g < n_nodes) ? (offsets[g + 1] - offsets[g]) : 0;
    }
    #pragma unroll
    for (int it = 0; it < 8; ++it) {
      int chunk = tid + it * 256;
      int r = chunk >> 5, c = chunk & 31;
      int g = base + r;
      uint4 v = make_uint4(0, 0, 0, 0);
      if (g < n_nodes) v = ((const uint4*)X1)[(size_t)g * 32 + c];
      *(uint4*)&xt[r * LDSR + c * 8] = v;
    }
    __syncthreads();

    const int lane = tid & 63;
    const int wid = tid >> 6;
    const int m16 = lane & 15;
    const int quad = lane >> 4;
    const int arow = wid * 16 + m16;
    const int lane8 = lane << 3;

    f32x4 acc[8];
    #pragma unroll
    for (int ot = 0; ot < 8; ++ot) acc[ot] = (f32x4){0.f, 0.f, 0.f, 0.f};

    #pragma unroll
    for (int k0i = 0; k0i < 8; ++k0i) {
      bf16x8 a = *(const bf16x8*)&xt[arow * LDSR + k0i * 32 + quad * 8];
      #pragma unroll
      for (int ot = 0; ot < 8; ++ot) {
        bf16x8 b = *(const bf16x8*)&Wp[((k0i * 8 + ot) << 9) + lane8];
        acc[ot] = __builtin_amdgcn_mfma_f32_16x16x32_bf16(a, b, acc[ot], 0, 0, 0);
      }
    }
    __syncthreads();

    #pragma unroll
    for (int ot = 0; ot < 8; ++ot) {
      int o = ot * 16 + m16;
      float bias = b1[o];
      #pragma unroll
      for (int r = 0; r < 4; ++r) {
        int m = wid * 16 + quad * 4 + r;
        float h = acc[ot][r] + (cnts[m] > 0 ? bias : 0.0f);
        xt[m * LDSR + 128 + o] = f2bf(h);
      }
    }
    #pragma unroll
    for (int it = 0; it < 8; ++it) {
      int chunk = tid + it * 256;
      int r = chunk >> 5, c = chunk & 31;
      int g = base + r;
      float4 v = make_float4(0.f, 0.f, 0.f, 0.f);
      if (g < n_nodes) v = ((const float4*)nfeats)[(size_t)g * 32 + c];
      ushort4 bv;
      bv.x = f2bf(v.x); bv.y = f2bf(v.y); bv.z = f2bf(v.z); bv.w = f2bf(v.w);
      *(ushort4*)&xt[r * LDSR + c * 4] = bv;
    }
    __syncthreads();

    #pragma unroll
    for (int ot = 0; ot < 8; ++ot) acc[ot] = (f32x4){0.f, 0.f, 0.f, 0.f};

    #pragma unroll
    for (int k0i = 0; k0i < 8; ++k0i) {
      bf16x8 a = *(const bf16x8*)&xt[arow * LDSR + k0i * 32 + quad * 8];
      #pragma unroll
      for (int ot = 0; ot < 8; ++ot) {
        bf16x8 b = *(const bf16x8*)&Wp[32768 + ((k0i * 8 + ot) << 9) + lane8];
        acc[ot] = __builtin_amdgcn_mfma_f32_16x16x32_bf16(a, b, acc[ot], 0, 0, 0);
      }
    }
    #pragma unroll
    for (int ot = 0; ot < 8; ++ot) {
      int o = ot * 16 + m16;
      float bias = b2[o];
      #pragma unroll
      for (int r = 0; r < 4; ++r) {
        int m = wid * 16 + quad * 4 + r;
        int g = base + m;
        if (g < n_nodes) {
          float v = acc[ot][r] + bias;
          out[(size_t)g * D + o] = v > 0.f ? v : 0.f;
        }
      }
    }
    __syncthreads();   // protect xt/cnts reuse on next grid-stride iteration
  }
}

extern "C" void kernel_launch(void* const* d_in, const int* in_sizes, int n_in,
                              void* d_out, int out_size, void* d_ws, size_t ws_size,
                              hipStream_t stream) {
  const float* nfeats = (const float*)d_in[0];
  const float* efeats = (const float*)d_in[1];
  const float* Wmsg_f = (const float*)d_in[2];
  const float* b1     = (const float*)d_in[3];
  const float* Wapp_f = (const float*)d_in[4];
  const float* b2     = (const float*)d_in[5];
  const int*   src    = (const int*)d_in[6];
  const int*   dst    = (const int*)d_in[7];
  const int n_nodes = in_sizes[0] / D;
  const int n_edges = in_sizes[6];

  char* ws = (char*)d_ws;
  size_t off = 0;
  unsigned short* X1 = (unsigned short*)(ws + off); off += (size_t)n_nodes * TWO_D * 2;
  unsigned short* Wp = (unsigned short*)(ws + off); off += (size_t)2 * D * TWO_D * 2;
  int* counts    = (int*)(ws + off); off += (size_t)n_nodes * 4;
  int* offsets   = (int*)(ws + off); off += (size_t)(n_nodes + 1) * 4;
  int* rank      = (int*)(ws + off); off += (size_t)n_edges * 4;
  int2* edge_list = (int2*)(ws + off); off += (size_t)n_edges * 8;
  int* bar       = (int*)(ws + off); off += 64;
  (void)ws_size; (void)n_in; (void)out_size;

  // Grid sized for guaranteed co-residency (software grid barrier).
  static int G = 0;
  if (G == 0) {
    int bpc = 0;
    if (hipOccupancyMaxActiveBlocksPerMultiprocessor(&bpc, gcn_fused, 256, 0) != hipSuccess || bpc < 1)
      bpc = 1;
    int dev = 0;
    hipGetDevice(&dev);
    int ncu = 0;
    if (hipDeviceGetAttribute(&ncu, hipDeviceAttributeMultiprocessorCount, dev) != hipSuccess || ncu < 1)
      ncu = 256;
    long g = (long)bpc * (long)ncu;
    if (g > 4096) g = 4096;
    G = (int)g;
  }

  hipMemsetAsync(bar, 0, sizeof(int), stream);
  gcn_fused<<<G, 256, 0, stream>>>(nfeats, efeats, Wmsg_f, b1, Wapp_f, b2, src, dst,
                                   X1, Wp, counts, offsets, rank, edge_list, bar,
                                   (float*)d_out, n_nodes, n_edges);
}

// Round 2
// 915.815 us; speedup vs baseline: 2.4168x; 2.4168x over previous
//
#include <hip/hip_runtime.h>

#define D 128
#define TWO_D 256
#define LDSR 264   // LDS row stride in bf16 units: 256 + 8 pad
#define MAXG 4096

typedef __attribute__((ext_vector_type(4))) float f32x4;
typedef __attribute__((ext_vector_type(8))) short bf16x8;

static __device__ __forceinline__ unsigned short f2bf(float x) {
  union { float f; unsigned u; } v; v.f = x;
  unsigned r = (v.u + 0x7fffu + ((v.u >> 16) & 1u)) >> 16;  // RNE
  return (unsigned short)r;
}

// Low-contention grid barrier (monotonic phase values b = 1,2,3,...).
// - arrival: each block release-stores b into its OWN slot (no RMW, no shared line)
// - block 0 polls all slots with RELAXED loads (no per-iteration cache invalidate!),
//   then ONE __threadfence() (acquire: pairs with all arrival release-stores),
//   then release-stores the broadcast flag.
// - other blocks spin RELAXED on the flag, then ONE __threadfence().
// Timeout failsafe converts a residency miscalculation into a wrong answer, not a hang.
static __device__ __forceinline__ void gbar(int* arrive, int* rel, int b,
                                            int GS) {
  const int tid = threadIdx.x;
  const int bid = blockIdx.x;
  __syncthreads();   // all prior LDS/global work in this block done
  if (bid == 0) {
    if (tid == 0)
      __hip_atomic_store(&arrive[0], b, __ATOMIC_RELEASE, __HIP_MEMORY_SCOPE_AGENT);
    for (int i = tid; i < GS; i += 256) {
      long long t0 = clock64();
      while (__hip_atomic_load(&arrive[i], __ATOMIC_RELAXED,
                               __HIP_MEMORY_SCOPE_AGENT) < b) {
        __builtin_amdgcn_s_sleep(2);
        if ((clock64() - t0) > 400000000LL) break;  // failsafe
      }
    }
    __threadfence();   // acquire side: makes all arrived blocks' writes visible
    __syncthreads();
    if (tid == 0)
      __hip_atomic_store(rel, b, __ATOMIC_RELEASE, __HIP_MEMORY_SCOPE_AGENT);
  } else {
    if (tid == 0) {
      __hip_atomic_store(&arrive[bid], b, __ATOMIC_RELEASE, __HIP_MEMORY_SCOPE_AGENT);
      long long t0 = clock64();
      while (__hip_atomic_load(rel, __ATOMIC_RELAXED,
                               __HIP_MEMORY_SCOPE_AGENT) < b) {
        __builtin_amdgcn_s_sleep(2);
        if ((clock64() - t0) > 400000000LL) break;  // failsafe
      }
    }
    __syncthreads();
    __threadfence();   // acquire side for every thread's subsequent reads
  }
}

__global__ __launch_bounds__(256, 4) void gcn_fused(
    const float* __restrict__ nfeats, const float* __restrict__ efeats,
    const float* __restrict__ wmsg, const float* __restrict__ b1,
    const float* __restrict__ wapp, const float* __restrict__ b2,
    const int* __restrict__ src, const int* __restrict__ dst,
    unsigned short* __restrict__ X1, unsigned short* __restrict__ Wp,
    int* __restrict__ d_counts, int* __restrict__ offsets,
    int* __restrict__ rank, int2* __restrict__ edge_list,
    int* __restrict__ arrive, int* __restrict__ rel,
    float* __restrict__ out, int n_nodes, int n_edges) {
  __shared__ unsigned short xt[64 * LDSR];
  __shared__ int cnts[64];
  __shared__ int sc[256];

  const int tid = threadIdx.x;
  const int bid = blockIdx.x;
  const int GS = gridDim.x;          // blocks (all co-resident)
  const int nthr = GS * 256;
  const int gtid = bid * 256 + tid;

  // ---- P0: pack both weights into MFMA-B-fragment order; zero counts ----
  for (int p = gtid; p < 65536; p += nthr) {
    int j = p & 7;
    int lane = (p >> 3) & 63;
    int ot = (p >> 9) & 7;
    int k0i = (p >> 12) & 7;
    int g = p >> 15;
    int o = ot * 16 + (lane & 15);
    int k = k0i * 32 + (lane >> 4) * 8 + j;
    const float* W = g ? wapp : wmsg;
    Wp[p] = f2bf(W[o * 256 + k]);
  }
  for (int p = gtid; p < n_nodes; p += nthr) d_counts[p] = 0;
  gbar(arrive, rel, 1, GS);

  // ---- P1: histogram + rank ----
  for (int e = gtid; e < n_edges; e += nthr)
    rank[e] = atomicAdd(&d_counts[dst[e]], 1);
  gbar(arrive, rel, 2, GS);

  // ---- P2: exclusive scan of counts -> offsets (block 0 only) ----
  if (bid == 0) {
    const int C = (n_nodes + 255) / 256;
    int lo = tid * C, hi = lo + C;
    if (lo > n_nodes) lo = n_nodes;
    if (hi > n_nodes) hi = n_nodes;
    int s = 0;
    for (int i = lo; i < hi; ++i) s += d_counts[i];
    sc[tid] = s;
    __syncthreads();
    for (int off = 1; off < 256; off <<= 1) {
      int v = (tid >= off) ? sc[tid - off] : 0;
      __syncthreads();
      sc[tid] += v;
      __syncthreads();
    }
    int base = (tid > 0) ? sc[tid - 1] : 0;
    for (int i = lo; i < hi; ++i) { int c = d_counts[i]; offsets[i] = base; base += c; }
    if (tid == 0) offsets[n_nodes] = n_edges;
  }
  gbar(arrive, rel, 3, GS);

  // ---- P3: scatter (atomic-free): edge_list[offsets[d]+rank[e]] = (e,src) ----
  for (int e = gtid; e < n_edges; e += nthr) {
    int d2 = dst[e];
    edge_list[offsets[d2] + rank[e]] = make_int2(e, src[e]);
  }
  gbar(arrive, rel, 4, GS);

  // ---- P4: gather — one wave per node, software-pipelined ----
  {
    const int lane = tid & 63;
    const int nwaves = nthr >> 6;
    const f32x4* nf4 = (const f32x4*)nfeats;
    const f32x4* ef4 = (const f32x4*)efeats;
    const int c32 = lane & 31;
    const int slot = lane >> 5;
    for (int w = (gtid >> 6); w < n_nodes; w += nwaves) {
      int beg = offsets[w], end = offsets[w + 1];
      int cnt = end - beg;
      f32x4 accn = (f32x4){0.f, 0.f, 0.f, 0.f};
      f32x4 acce = (f32x4){0.f, 0.f, 0.f, 0.f};
      for (int j0 = beg; j0 < end; j0 += 64) {
        int njj = end - j0; if (njj > 64) njj = 64;
        int e = 0, s = 0;
        if (lane < njj) { int2 es = edge_list[j0 + lane]; e = es.x; s = es.y; }
        int i0 = slot, i1 = 2 + slot;
        int ee0 = __shfl(e, i0), ss0 = __shfl(s, i0);
        int ee1 = __shfl(e, i1), ss1 = __shfl(s, i1);
        bool v0 = i0 < njj, v1 = i1 < njj;
        f32x4 a0 = (f32x4){0.f,0.f,0.f,0.f}, b0 = a0, a1 = a0, b1v = a0;
        if (v0) { a0 = nf4[(size_t)ss0 * 32 + c32];
                  b0 = __builtin_nontemporal_load(&ef4[(size_t)ee0 * 32 + c32]); }
        if (v1) { a1 = nf4[(size_t)ss1 * 32 + c32];
                  b1v = __builtin_nontemporal_load(&ef4[(size_t)ee1 * 32 + c32]); }
        for (int p = 0; p < njj; p += 4) {
          int n0 = (p + 4 + slot) & 63, n1 = (p + 6 + slot) & 63;
          int eeN0 = __shfl(e, n0), ssN0 = __shfl(s, n0);
          int eeN1 = __shfl(e, n1), ssN1 = __shfl(s, n1);
          bool u0 = p + 4 + slot < njj, u1 = p + 6 + slot < njj;
          f32x4 aN0 = (f32x4){0.f,0.f,0.f,0.f}, bN0 = aN0, aN1 = aN0, bN1 = aN0;
          if (u0) { aN0 = nf4[(size_t)ssN0 * 32 + c32];
                    bN0 = __builtin_nontemporal_load(&ef4[(size_t)eeN0 * 32 + c32]); }
          if (u1) { aN1 = nf4[(size_t)ssN1 * 32 + c32];
                    bN1 = __builtin_nontemporal_load(&ef4[(size_t)eeN1 * 32 + c32]); }
          if (v0) { accn += a0; acce += b0; }
          if (v1) { accn += a1; acce += b1v; }
          a0 = aN0; b0 = bN0; a1 = aN1; b1v = bN1; v0 = u0; v1 = u1;
        }
      }
      #pragma unroll
      for (int k = 0; k < 4; ++k) {
        accn[k] += __shfl_xor(accn[k], 32);
        acce[k] += __shfl_xor(acce[k], 32);
      }
      float inv = (cnt > 0) ? 1.0f / (float)cnt : 0.0f;
      f32x4 vv = (lane < 32) ? accn : acce;
      ushort4 o4;
      o4.x = f2bf(vv[0] * inv); o4.y = f2bf(vv[1] * inv);
      o4.z = f2bf(vv[2] * inv); o4.w = f2bf(vv[3] * inv);
      ((ushort4*)(X1 + (size_t)w * TWO_D))[lane] = o4;
    }
  }
  gbar(arrive, rel, 5, GS);

  // ---- P5: node GEMMs (grid-stride over 64-node tiles) ----
  const int nblk = (n_nodes + 63) / 64;
  for (int blk = bid; blk < nblk; blk += GS) {
    const int base = blk * 64;
    if (tid < 64) {
      int g = base + tid;
      cnts[tid] = (g < n_nodes) ? (offsets[g + 1] - offsets[g]) : 0;
    }
    #pragma unroll
    for (int it = 0; it < 8; ++it) {
      int chunk = tid + it * 256;
      int r = chunk >> 5, c = chunk & 31;
      int g = base + r;
      uint4 v = make_uint4(0, 0, 0, 0);
      if (g < n_nodes) v = ((const uint4*)X1)[(size_t)g * 32 + c];
      *(uint4*)&xt[r * LDSR + c * 8] = v;
    }
    __syncthreads();

    const int lane = tid & 63;
    const int wid = tid >> 6;
    const int m16 = lane & 15;
    const int quad = lane >> 4;
    const int arow = wid * 16 + m16;
    const int lane8 = lane << 3;

    f32x4 acc[8];
    #pragma unroll
    for (int ot = 0; ot < 8; ++ot) acc[ot] = (f32x4){0.f, 0.f, 0.f, 0.f};

    #pragma unroll
    for (int k0i = 0; k0i < 8; ++k0i) {
      bf16x8 a = *(const bf16x8*)&xt[arow * LDSR + k0i * 32 + quad * 8];
      #pragma unroll
      for (int ot = 0; ot < 8; ++ot) {
        bf16x8 b = *(const bf16x8*)&Wp[((k0i * 8 + ot) << 9) + lane8];
        acc[ot] = __builtin_amdgcn_mfma_f32_16x16x32_bf16(a, b, acc[ot], 0, 0, 0);
      }
    }
    __syncthreads();

    #pragma unroll
    for (int ot = 0; ot < 8; ++ot) {
      int o = ot * 16 + m16;
      float bias = b1[o];
      #pragma unroll
      for (int r = 0; r < 4; ++r) {
        int m = wid * 16 + quad * 4 + r;
        float h = acc[ot][r] + (cnts[m] > 0 ? bias : 0.0f);
        xt[m * LDSR + 128 + o] = f2bf(h);
      }
    }
    #pragma unroll
    for (int it = 0; it < 8; ++it) {
      int chunk = tid + it * 256;
      int r = chunk >> 5, c = chunk & 31;
      int g = base + r;
      float4 v = make_float4(0.f, 0.f, 0.f, 0.f);
      if (g < n_nodes) v = ((const float4*)nfeats)[(size_t)g * 32 + c];
      ushort4 bv;
      bv.x = f2bf(v.x); bv.y = f2bf(v.y); bv.z = f2bf(v.z); bv.w = f2bf(v.w);
      *(ushort4*)&xt[r * LDSR + c * 4] = bv;
    }
    __syncthreads();

    #pragma unroll
    for (int ot = 0; ot < 8; ++ot) acc[ot] = (f32x4){0.f, 0.f, 0.f, 0.f};

    #pragma unroll
    for (int k0i = 0; k0i < 8; ++k0i) {
      bf16x8 a = *(const bf16x8*)&xt[arow * LDSR + k0i * 32 + quad * 8];
      #pragma unroll
      for (int ot = 0; ot < 8; ++ot) {
        bf16x8 b = *(const bf16x8*)&Wp[32768 + ((k0i * 8 + ot) << 9) + lane8];
        acc[ot] = __builtin_amdgcn_mfma_f32_16x16x32_bf16(a, b, acc[ot], 0, 0, 0);
      }
    }
    #pragma unroll
    for (int ot = 0; ot < 8; ++ot) {
      int o = ot * 16 + m16;
      float bias = b2[o];
      #pragma unroll
      for (int r = 0; r < 4; ++r) {
        int m = wid * 16 + quad * 4 + r;
        int g = base + m;
        if (g < n_nodes) {
          float v = acc[ot][r] + bias;
          out[(size_t)g * D + o] = v > 0.f ? v : 0.f;
        }
      }
    }
    __syncthreads();   // protect xt/cnts reuse on next grid-stride iteration
  }
}

extern "C" void kernel_launch(void* const* d_in, const int* in_sizes, int n_in,
                              void* d_out, int out_size, void* d_ws, size_t ws_size,
                              hipStream_t stream) {
  const float* nfeats = (const float*)d_in[0];
  const float* efeats = (const float*)d_in[1];
  const float* Wmsg_f = (const float*)d_in[2];
  const float* b1     = (const float*)d_in[3];
  const float* Wapp_f = (const float*)d_in[4];
  const float* b2     = (const float*)d_in[5];
  const int*   src    = (const int*)d_in[6];
  const int*   dst    = (const int*)d_in[7];
  const int n_nodes = in_sizes[0] / D;
  const int n_edges = in_sizes[6];

  char* ws = (char*)d_ws;
  size_t off = 0;
  unsigned short* X1 = (unsigned short*)(ws + off); off += (size_t)n_nodes * TWO_D * 2;
  unsigned short* Wp = (unsigned short*)(ws + off); off += (size_t)2 * D * TWO_D * 2;
  int* counts    = (int*)(ws + off); off += (size_t)n_nodes * 4;
  int* offsets   = (int*)(ws + off); off += (size_t)(n_nodes + 1) * 4;
  int* rank      = (int*)(ws + off); off += (size_t)n_edges * 4;
  int2* edge_list = (int2*)(ws + off); off += (size_t)n_edges * 8;
  int* arrive    = (int*)(ws + off); off += (size_t)MAXG * 4;
  int* rel       = (int*)(ws + off); off += 64;
  (void)ws_size; (void)n_in; (void)out_size;

  // Grid sized for guaranteed co-residency (software grid barrier).
  static int G = 0;
  if (G == 0) {
    int bpc = 0;
    if (hipOccupancyMaxActiveBlocksPerMultiprocessor(&bpc, gcn_fused, 256, 0) != hipSuccess || bpc < 1)
      bpc = 1;
    int dev = 0;
    hipGetDevice(&dev);
    int ncu = 0;
    if (hipDeviceGetAttribute(&ncu, hipDeviceAttributeMultiprocessorCount, dev) != hipSuccess || ncu < 1)
      ncu = 256;
    long g = (long)bpc * (long)ncu;
    if (g > MAXG) g = MAXG;
    G = (int)g;
  }

  hipMemsetAsync(arrive, 0, ((size_t)MAXG + 16) * 4, stream);
  gcn_fused<<<G, 256, 0, stream>>>(nfeats, efeats, Wmsg_f, b1, Wapp_f, b2, src, dst,
                                   X1, Wp, counts, offsets, rank, edge_list,
                                   arrive, rel, (float*)d_out, n_nodes, n_edges);
}

// Round 3
// 820.641 us; speedup vs baseline: 2.6971x; 1.1160x over previous
//
#include <hip/hip_runtime.h>

#define D 128
#define TWO_D 256
#define LDSR 264   // LDS row stride in bf16 units: 256 + 8 pad
#define MAXG 4096

typedef __attribute__((ext_vector_type(4))) float f32x4;
typedef __attribute__((ext_vector_type(8))) short bf16x8;

static __device__ __forceinline__ unsigned short f2bf(float x) {
  union { float f; unsigned u; } v; v.f = x;
  unsigned r = (v.u + 0x7fffu + ((v.u >> 16) & 1u)) >> 16;  // RNE
  return (unsigned short)r;
}

// Low-contention grid barrier (monotonic phase values b = 1,2,3,...).
// Distributed arrival slots + relaxed polling (no per-poll cache invalidate),
// single fence on exit. Timeout failsafe: residency miscalculation -> wrong
// answer, not a hang.
static __device__ __forceinline__ void gbar(int* arrive, int* rel, int b,
                                            int GS) {
  const int tid = threadIdx.x;
  const int bid = blockIdx.x;
  __syncthreads();
  if (bid == 0) {
    if (tid == 0)
      __hip_atomic_store(&arrive[0], b, __ATOMIC_RELEASE, __HIP_MEMORY_SCOPE_AGENT);
    for (int i = tid; i < GS; i += 256) {
      long long t0 = clock64();
      while (__hip_atomic_load(&arrive[i], __ATOMIC_RELAXED,
                               __HIP_MEMORY_SCOPE_AGENT) < b) {
        __builtin_amdgcn_s_sleep(2);
        if ((clock64() - t0) > 400000000LL) break;  // failsafe
      }
    }
    __threadfence();
    __syncthreads();
    if (tid == 0)
      __hip_atomic_store(rel, b, __ATOMIC_RELEASE, __HIP_MEMORY_SCOPE_AGENT);
  } else {
    if (tid == 0) {
      __hip_atomic_store(&arrive[bid], b, __ATOMIC_RELEASE, __HIP_MEMORY_SCOPE_AGENT);
      long long t0 = clock64();
      while (__hip_atomic_load(rel, __ATOMIC_RELAXED,
                               __HIP_MEMORY_SCOPE_AGENT) < b) {
        __builtin_amdgcn_s_sleep(2);
        if ((clock64() - t0) > 400000000LL) break;  // failsafe
      }
    }
    __syncthreads();
    __threadfence();
  }
}

__global__ __launch_bounds__(256, 4) void gcn_fused(
    const float* __restrict__ nfeats, const float* __restrict__ efeats,
    const float* __restrict__ wmsg, const float* __restrict__ b1,
    const float* __restrict__ wapp, const float* __restrict__ b2,
    const int* __restrict__ src, const int* __restrict__ dst,
    unsigned short* __restrict__ X1, unsigned short* __restrict__ Wp,
    int* __restrict__ d_counts, int* __restrict__ offsets,
    int* __restrict__ rank, int2* __restrict__ edge_list,
    int* __restrict__ partial,
    int* __restrict__ arrive, int* __restrict__ rel,
    float* __restrict__ out, int n_nodes, int n_edges) {
  // 32-row GEMM tile (not 64): keeps LDS ~18 KB so 8 blocks/CU stay resident,
  // doubling gather-phase TLP vs the 64-row/35 KB variant.
  __shared__ unsigned short xt[32 * LDSR];
  __shared__ int cnts[32];
  __shared__ int sc[256];
  __shared__ int pb[64];

  const int tid = threadIdx.x;
  const int bid = blockIdx.x;
  const int GS = gridDim.x;          // blocks (all co-resident)
  const int nthr = GS * 256;
  const int gtid = bid * 256 + tid;

  // ---- P0: pack both weights into MFMA-B-fragment order ----
  // (d_counts zeroed by hipMemsetAsync before launch; Wp-pack -> P5 ordering
  //  is covered transitively by the later barriers, so no barrier here.)
  for (int p = gtid; p < 65536; p += nthr) {
    int j = p & 7;
    int lane = (p >> 3) & 63;
    int ot = (p >> 9) & 7;
    int k0i = (p >> 12) & 7;
    int g = p >> 15;
    int o = ot * 16 + (lane & 15);
    int k = k0i * 32 + (lane >> 4) * 8 + j;
    const float* W = g ? wapp : wmsg;
    Wp[p] = f2bf(W[o * 256 + k]);
  }

  // ---- P1: histogram + rank ----
  for (int e = gtid; e < n_edges; e += nthr)
    rank[e] = atomicAdd(&d_counts[dst[e]], 1);
  gbar(arrive, rel, 1, GS);

  // ---- P2a: per-block partial sums (1024 counts/block, parallel) ----
  const int nbScan = (n_nodes + 1023) >> 10;   // 49
  if (bid < nbScan) {
    int g0 = bid * 1024 + tid * 4;
    int s = 0;
    #pragma unroll
    for (int j = 0; j < 4; ++j) { int g = g0 + j; if (g < n_nodes) s += d_counts[g]; }
    sc[tid] = s;
    __syncthreads();
    for (int off = 128; off > 0; off >>= 1) {
      if (tid < off) sc[tid] += sc[tid + off];
      __syncthreads();
    }
    if (tid == 0) partial[bid] = sc[0];
  }
  gbar(arrive, rel, 2, GS);

  // ---- P2b: per-block exclusive scan + write offsets (parallel) ----
  if (bid < nbScan) {
    if (tid < nbScan) pb[tid] = partial[tid];
    __syncthreads();
    int base = 0;
    for (int k = 0; k < bid; ++k) base += pb[k];
    int g0 = bid * 1024 + tid * 4;
    int c0 = (g0 + 0 < n_nodes) ? d_counts[g0 + 0] : 0;
    int c1 = (g0 + 1 < n_nodes) ? d_counts[g0 + 1] : 0;
    int c2 = (g0 + 2 < n_nodes) ? d_counts[g0 + 2] : 0;
    int c3 = (g0 + 3 < n_nodes) ? d_counts[g0 + 3] : 0;
    sc[tid] = c0 + c1 + c2 + c3;
    __syncthreads();
    for (int off = 1; off < 256; off <<= 1) {
      int v = (tid >= off) ? sc[tid - off] : 0;
      __syncthreads();
      sc[tid] += v;
      __syncthreads();
    }
    int texc = base + ((tid > 0) ? sc[tid - 1] : 0);
    if (g0 + 0 < n_nodes) offsets[g0 + 0] = texc;
    if (g0 + 1 < n_nodes) offsets[g0 + 1] = texc + c0;
    if (g0 + 2 < n_nodes) offsets[g0 + 2] = texc + c0 + c1;
    if (g0 + 3 < n_nodes) offsets[g0 + 3] = texc + c0 + c1 + c2;
    if (bid == 0 && tid == 0) offsets[n_nodes] = n_edges;
  }
  gbar(arrive, rel, 3, GS);

  // ---- P3: scatter (atomic-free): edge_list[offsets[d]+rank[e]] = (e,src) ----
  for (int e = gtid; e < n_edges; e += nthr) {
    int d2 = dst[e];
    edge_list[offsets[d2] + rank[e]] = make_int2(e, src[e]);
  }
  gbar(arrive, rel, 4, GS);

  // ---- P4: gather — one wave per node, software-pipelined ----
  {
    const int lane = tid & 63;
    const int nwaves = nthr >> 6;
    const f32x4* nf4 = (const f32x4*)nfeats;
    const f32x4* ef4 = (const f32x4*)efeats;
    const int c32 = lane & 31;
    const int slot = lane >> 5;
    for (int w = (gtid >> 6); w < n_nodes; w += nwaves) {
      int beg = offsets[w], end = offsets[w + 1];
      int cnt = end - beg;
      f32x4 accn = (f32x4){0.f, 0.f, 0.f, 0.f};
      f32x4 acce = (f32x4){0.f, 0.f, 0.f, 0.f};
      for (int j0 = beg; j0 < end; j0 += 64) {
        int njj = end - j0; if (njj > 64) njj = 64;
        int e = 0, s = 0;
        if (lane < njj) { int2 es = edge_list[j0 + lane]; e = es.x; s = es.y; }
        int i0 = slot, i1 = 2 + slot;
        int ee0 = __shfl(e, i0), ss0 = __shfl(s, i0);
        int ee1 = __shfl(e, i1), ss1 = __shfl(s, i1);
        bool v0 = i0 < njj, v1 = i1 < njj;
        f32x4 a0 = (f32x4){0.f,0.f,0.f,0.f}, b0 = a0, a1 = a0, b1v = a0;
        if (v0) { a0 = nf4[(size_t)ss0 * 32 + c32];
                  b0 = __builtin_nontemporal_load(&ef4[(size_t)ee0 * 32 + c32]); }
        if (v1) { a1 = nf4[(size_t)ss1 * 32 + c32];
                  b1v = __builtin_nontemporal_load(&ef4[(size_t)ee1 * 32 + c32]); }
        for (int p = 0; p < njj; p += 4) {
          int n0 = (p + 4 + slot) & 63, n1 = (p + 6 + slot) & 63;
          int eeN0 = __shfl(e, n0), ssN0 = __shfl(s, n0);
          int eeN1 = __shfl(e, n1), ssN1 = __shfl(s, n1);
          bool u0 = p + 4 + slot < njj, u1 = p + 6 + slot < njj;
          f32x4 aN0 = (f32x4){0.f,0.f,0.f,0.f}, bN0 = aN0, aN1 = aN0, bN1 = aN0;
          if (u0) { aN0 = nf4[(size_t)ssN0 * 32 + c32];
                    bN0 = __builtin_nontemporal_load(&ef4[(size_t)eeN0 * 32 + c32]); }
          if (u1) { aN1 = nf4[(size_t)ssN1 * 32 + c32];
                    bN1 = __builtin_nontemporal_load(&ef4[(size_t)eeN1 * 32 + c32]); }
          if (v0) { accn += a0; acce += b0; }
          if (v1) { accn += a1; acce += b1v; }
          a0 = aN0; b0 = bN0; a1 = aN1; b1v = bN1; v0 = u0; v1 = u1;
        }
      }
      #pragma unroll
      for (int k = 0; k < 4; ++k) {
        accn[k] += __shfl_xor(accn[k], 32);
        acce[k] += __shfl_xor(acce[k], 32);
      }
      float inv = (cnt > 0) ? 1.0f / (float)cnt : 0.0f;
      f32x4 vv = (lane < 32) ? accn : acce;
      ushort4 o4;
      o4.x = f2bf(vv[0] * inv); o4.y = f2bf(vv[1] * inv);
      o4.z = f2bf(vv[2] * inv); o4.w = f2bf(vv[3] * inv);
      ((ushort4*)(X1 + (size_t)w * TWO_D))[lane] = o4;
    }
  }
  gbar(arrive, rel, 5, GS);

  // ---- P5: node GEMMs, 32-row tiles; waves split (row-group x output-half) ----
  {
    const int lane = tid & 63;
    const int wid = tid >> 6;
    const int m16 = lane & 15;
    const int quad = lane >> 4;
    const int rowgrp = wid >> 1;       // 0: rows 0-15, 1: rows 16-31
    const int oh = wid & 1;            // output-half: ot = oh*4 + otl
    const int arow = rowgrp * 16 + m16;
    const int lane8 = lane << 3;

    const int nblk = (n_nodes + 31) >> 5;
    for (int blk = bid; blk < nblk; blk += GS) {
      const int base = blk * 32;
      if (tid < 32) {
        int g = base + tid;
        cnts[tid] = (g < n_nodes) ? (offsets[g + 1] - offsets[g]) : 0;
      }
      // stage X1 tile: 32 rows x 32 uint4 (256 bf16 cols)
      #pragma unroll
      for (int it = 0; it < 4; ++it) {
        int chunk = tid + it * 256;
        int r = chunk >> 5, c = chunk & 31;
        int g = base + r;
        uint4 v = make_uint4(0, 0, 0, 0);
        if (g < n_nodes) v = ((const uint4*)X1)[(size_t)g * 32 + c];
        *(uint4*)&xt[r * LDSR + c * 8] = v;
      }
      __syncthreads();

      f32x4 acc[4];
      #pragma unroll
      for (int otl = 0; otl < 4; ++otl) acc[otl] = (f32x4){0.f, 0.f, 0.f, 0.f};

      #pragma unroll
      for (int k0i = 0; k0i < 8; ++k0i) {
        bf16x8 a = *(const bf16x8*)&xt[arow * LDSR + k0i * 32 + quad * 8];
        #pragma unroll
        for (int otl = 0; otl < 4; ++otl) {
          int ot = oh * 4 + otl;
          bf16x8 b = *(const bf16x8*)&Wp[((k0i * 8 + ot) << 9) + lane8];
          acc[otl] = __builtin_amdgcn_mfma_f32_16x16x32_bf16(a, b, acc[otl], 0, 0, 0);
        }
      }
      __syncthreads();   // all A-reads done before overwriting xt

      #pragma unroll
      for (int otl = 0; otl < 4; ++otl) {
        int o = (oh * 4 + otl) * 16 + m16;
        float bias = b1[o];
        #pragma unroll
        for (int r = 0; r < 4; ++r) {
          int m = rowgrp * 16 + quad * 4 + r;
          float h = acc[otl][r] + (cnts[m] > 0 ? bias : 0.0f);
          xt[m * LDSR + 128 + o] = f2bf(h);   // cols 128-255
        }
      }
      // stage nfeats (bf16) into cols 0-127
      #pragma unroll
      for (int it = 0; it < 4; ++it) {
        int chunk = tid + it * 256;
        int r = chunk >> 5, c = chunk & 31;
        int g = base + r;
        float4 v = make_float4(0.f, 0.f, 0.f, 0.f);
        if (g < n_nodes) v = ((const float4*)nfeats)[(size_t)g * 32 + c];
        ushort4 bv;
        bv.x = f2bf(v.x); bv.y = f2bf(v.y); bv.z = f2bf(v.z); bv.w = f2bf(v.w);
        *(ushort4*)&xt[r * LDSR + c * 4] = bv;
      }
      __syncthreads();

      #pragma unroll
      for (int otl = 0; otl < 4; ++otl) acc[otl] = (f32x4){0.f, 0.f, 0.f, 0.f};

      #pragma unroll
      for (int k0i = 0; k0i < 8; ++k0i) {
        bf16x8 a = *(const bf16x8*)&xt[arow * LDSR + k0i * 32 + quad * 8];
        #pragma unroll
        for (int otl = 0; otl < 4; ++otl) {
          int ot = oh * 4 + otl;
          bf16x8 b = *(const bf16x8*)&Wp[32768 + ((k0i * 8 + ot) << 9) + lane8];
          acc[otl] = __builtin_amdgcn_mfma_f32_16x16x32_bf16(a, b, acc[otl], 0, 0, 0);
        }
      }
      #pragma unroll
      for (int otl = 0; otl < 4; ++otl) {
        int o = (oh * 4 + otl) * 16 + m16;
        float bias = b2[o];
        #pragma unroll
        for (int r = 0; r < 4; ++r) {
          int m = rowgrp * 16 + quad * 4 + r;
          int g = base + m;
          if (g < n_nodes) {
            float v = acc[otl][r] + bias;
            out[(size_t)g * D + o] = v > 0.f ? v : 0.f;
          }
        }
      }
      __syncthreads();   // protect xt/cnts reuse on next grid-stride iteration
    }
  }
}

extern "C" void kernel_launch(void* const* d_in, const int* in_sizes, int n_in,
                              void* d_out, int out_size, void* d_ws, size_t ws_size,
                              hipStream_t stream) {
  const float* nfeats = (const float*)d_in[0];
  const float* efeats = (const float*)d_in[1];
  const float* Wmsg_f = (const float*)d_in[2];
  const float* b1     = (const float*)d_in[3];
  const float* Wapp_f = (const float*)d_in[4];
  const float* b2     = (const float*)d_in[5];
  const int*   src    = (const int*)d_in[6];
  const int*   dst    = (const int*)d_in[7];
  const int n_nodes = in_sizes[0] / D;
  const int n_edges = in_sizes[6];

  char* ws = (char*)d_ws;
  size_t off = 0;
  unsigned short* X1 = (unsigned short*)(ws + off); off += (size_t)n_nodes * TWO_D * 2;
  unsigned short* Wp = (unsigned short*)(ws + off); off += (size_t)2 * D * TWO_D * 2;
  int* counts    = (int*)(ws + off); off += (size_t)n_nodes * 4;
  int* offsets   = (int*)(ws + off); off += (size_t)(n_nodes + 1) * 4;
  int* rank      = (int*)(ws + off); off += (size_t)n_edges * 4;
  int2* edge_list = (int2*)(ws + off); off += (size_t)n_edges * 8;
  int* partial   = (int*)(ws + off); off += 64 * 4;
  int* arrive    = (int*)(ws + off); off += (size_t)MAXG * 4;
  int* rel       = (int*)(ws + off); off += 64;
  (void)ws_size; (void)n_in; (void)out_size;

  // Grid sized for guaranteed co-residency (software grid barrier).
  static int G = 0;
  if (G == 0) {
    int bpc = 0;
    if (hipOccupancyMaxActiveBlocksPerMultiprocessor(&bpc, gcn_fused, 256, 0) != hipSuccess || bpc < 1)
      bpc = 1;
    int dev = 0;
    hipGetDevice(&dev);
    int ncu = 0;
    if (hipDeviceGetAttribute(&ncu, hipDeviceAttributeMultiprocessorCount, dev) != hipSuccess || ncu < 1)
      ncu = 256;
    long g = (long)bpc * (long)ncu;
    if (g > MAXG) g = MAXG;
    G = (int)g;
  }

  hipMemsetAsync(counts, 0, (size_t)n_nodes * 4, stream);
  hipMemsetAsync(arrive, 0, ((size_t)MAXG + 16) * 4, stream);
  gcn_fused<<<G, 256, 0, stream>>>(nfeats, efeats, Wmsg_f, b1, Wapp_f, b2, src, dst,
                                   X1, Wp, counts, offsets, rank, edge_list,
                                   partial, arrive, rel,
                                   (float*)d_out, n_nodes, n_edges);
}

// Round 4
// 552.258 us; speedup vs baseline: 4.0079x; 1.4860x over previous
//
#include <hip/hip_runtime.h>

#define D 128
#define TWO_D 256
#define LDSR 264   // LDS row stride in bf16 units: 256 + 8 pad

typedef __attribute__((ext_vector_type(4))) float f32x4;
typedef __attribute__((ext_vector_type(8))) short bf16x8;

static __device__ __forceinline__ unsigned short f2bf(float x) {
  union { float f; unsigned u; } v; v.f = x;
  unsigned r = (v.u + 0x7fffu + ((v.u >> 16) & 1u)) >> 16;  // RNE
  return (unsigned short)r;
}

// ---- K1: weight pack (first 65536 threads) + histogram/rank (all edges) ----
// counts zeroed by hipMemsetAsync before this launch.
__global__ void prep_hist(const float* __restrict__ wmsg,
                          const float* __restrict__ wapp,
                          unsigned short* __restrict__ Wp,
                          const int* __restrict__ dst,
                          int* __restrict__ counts, int* __restrict__ rank,
                          int n_edges) {
  int p = blockIdx.x * blockDim.x + threadIdx.x;
  if (p < 65536) {
    int j = p & 7;
    int lane = (p >> 3) & 63;
    int ot = (p >> 9) & 7;
    int k0i = (p >> 12) & 7;
    int g = p >> 15;
    int o = ot * 16 + (lane & 15);
    int k = k0i * 32 + (lane >> 4) * 8 + j;
    const float* W = g ? wapp : wmsg;
    Wp[p] = f2bf(W[o * 256 + k]);
  }
  if (p < n_edges) rank[p] = atomicAdd(&counts[dst[p]], 1);
}

// ---- K2: per-block partial sums (1024 counts/block) ----
__global__ void scan_part(const int* __restrict__ counts, int* __restrict__ partial,
                          int n) {
  __shared__ int lds[256];
  int b = blockIdx.x, t = threadIdx.x;
  int g0 = b * 1024 + t * 4;
  int s = 0;
  #pragma unroll
  for (int j = 0; j < 4; ++j) { int g = g0 + j; if (g < n) s += counts[g]; }
  lds[t] = s;
  __syncthreads();
  for (int off = 128; off > 0; off >>= 1) {
    if (t < off) lds[t] += lds[t + off];
    __syncthreads();
  }
  if (t == 0) partial[b] = lds[0];
}

// ---- K3: per-block exclusive scan + write offsets ----
__global__ void scan_write(const int* __restrict__ counts, const int* __restrict__ partial,
                           int* __restrict__ offsets, int n, int n_edges, int nb) {
  __shared__ int lds[256];
  __shared__ int pb[64];
  int b = blockIdx.x, t = threadIdx.x;
  if (t < nb) pb[t] = partial[t];
  __syncthreads();
  int base = 0;
  for (int k = 0; k < b; ++k) base += pb[k];
  int g0 = b * 1024 + t * 4;
  int c0 = (g0 + 0 < n) ? counts[g0 + 0] : 0;
  int c1 = (g0 + 1 < n) ? counts[g0 + 1] : 0;
  int c2 = (g0 + 2 < n) ? counts[g0 + 2] : 0;
  int c3 = (g0 + 3 < n) ? counts[g0 + 3] : 0;
  lds[t] = c0 + c1 + c2 + c3;
  __syncthreads();
  for (int off = 1; off < 256; off <<= 1) {
    int v = (t >= off) ? lds[t - off] : 0;
    __syncthreads();
    lds[t] += v;
    __syncthreads();
  }
  int texc = base + ((t > 0) ? lds[t - 1] : 0);
  if (g0 + 0 < n) offsets[g0 + 0] = texc;
  if (g0 + 1 < n) offsets[g0 + 1] = texc + c0;
  if (g0 + 2 < n) offsets[g0 + 2] = texc + c0 + c1;
  if (g0 + 3 < n) offsets[g0 + 3] = texc + c0 + c1 + c2;
  if (b == 0 && t == 0) offsets[n] = n_edges;
}

// ---- K4: scatter (atomic-free): edge_list[offsets[d]+rank[e]] = (e, src[e]) ----
__global__ void scatter_kernel(const int* __restrict__ dst, const int* __restrict__ src,
                               const int* __restrict__ rank,
                               const int* __restrict__ offsets,
                               int2* __restrict__ edge_list, int n_edges) {
  int e = blockIdx.x * blockDim.x + threadIdx.x;
  if (e < n_edges) {
    int d = dst[e];
    edge_list[offsets[d] + rank[e]] = make_int2(e, src[e]);
  }
}

// ---- K5: fused gather + node GEMMs.
// One block = 64 nodes. Each of 4 waves gathers 16 nodes (pipelined row loads)
// straight into the LDS GEMM tile (same layout X1 staging produced), then the
// proven MFMA body runs. No X1 global round-trip, no grid sync needed:
// a block only consumes what it produced. MFMA of one block overlaps gather
// loads of co-resident blocks on the same CU.
__global__ __launch_bounds__(256, 4) void gather_gemm(
    const float* __restrict__ nfeats, const float* __restrict__ efeats,
    const int2* __restrict__ edge_list, const int* __restrict__ offsets,
    const unsigned short* __restrict__ Wp,
    const float* __restrict__ b1, const float* __restrict__ b2,
    float* __restrict__ out, int n_nodes) {
  __shared__ unsigned short xt[64 * LDSR];
  __shared__ int cnts[64];
  const int tid = threadIdx.x;
  const int base = blockIdx.x * 64;
  const int lane = tid & 63;
  const int wid = tid >> 6;

  // ---- gather phase: wave wid fills rows wid*16 .. wid*16+15 ----
  {
    const f32x4* nf4 = (const f32x4*)nfeats;
    const f32x4* ef4 = (const f32x4*)efeats;
    const int c32 = lane & 31;
    const int slot = lane >> 5;
    for (int i = 0; i < 16; ++i) {
      const int row = wid * 16 + i;
      const int w = base + row;
      int beg = 0, end = 0;
      if (w < n_nodes) { beg = offsets[w]; end = offsets[w + 1]; }
      const int cnt = end - beg;
      f32x4 accn = (f32x4){0.f, 0.f, 0.f, 0.f};
      f32x4 acce = (f32x4){0.f, 0.f, 0.f, 0.f};
      for (int j0 = beg; j0 < end; j0 += 64) {
        int nj = end - j0; if (nj > 64) nj = 64;
        int e = 0, s = 0;
        if (lane < nj) { int2 es = edge_list[j0 + lane]; e = es.x; s = es.y; }
        int i0 = slot, i1 = 2 + slot;
        int ee0 = __shfl(e, i0), ss0 = __shfl(s, i0);
        int ee1 = __shfl(e, i1), ss1 = __shfl(s, i1);
        bool v0 = i0 < nj, v1 = i1 < nj;
        f32x4 a0 = (f32x4){0.f,0.f,0.f,0.f}, b0 = a0, a1 = a0, b1v = a0;
        if (v0) { a0 = nf4[(size_t)ss0 * 32 + c32];
                  b0 = __builtin_nontemporal_load(&ef4[(size_t)ee0 * 32 + c32]); }
        if (v1) { a1 = nf4[(size_t)ss1 * 32 + c32];
                  b1v = __builtin_nontemporal_load(&ef4[(size_t)ee1 * 32 + c32]); }
        for (int p = 0; p < nj; p += 4) {
          int n0 = (p + 4 + slot) & 63, n1 = (p + 6 + slot) & 63;
          int eeN0 = __shfl(e, n0), ssN0 = __shfl(s, n0);
          int eeN1 = __shfl(e, n1), ssN1 = __shfl(s, n1);
          bool u0 = p + 4 + slot < nj, u1 = p + 6 + slot < nj;
          f32x4 aN0 = (f32x4){0.f,0.f,0.f,0.f}, bN0 = aN0, aN1 = aN0, bN1 = aN0;
          if (u0) { aN0 = nf4[(size_t)ssN0 * 32 + c32];
                    bN0 = __builtin_nontemporal_load(&ef4[(size_t)eeN0 * 32 + c32]); }
          if (u1) { aN1 = nf4[(size_t)ssN1 * 32 + c32];
                    bN1 = __builtin_nontemporal_load(&ef4[(size_t)eeN1 * 32 + c32]); }
          if (v0) { accn += a0; acce += b0; }
          if (v1) { accn += a1; acce += b1v; }
          a0 = aN0; b0 = bN0; a1 = aN1; b1v = bN1; v0 = u0; v1 = u1;
        }
      }
      #pragma unroll
      for (int k = 0; k < 4; ++k) {
        accn[k] += __shfl_xor(accn[k], 32);
        acce[k] += __shfl_xor(acce[k], 32);
      }
      if (lane == 0) cnts[row] = cnt;
      float inv = (cnt > 0) ? 1.0f / (float)cnt : 0.0f;
      f32x4 vv = (lane < 32) ? accn : acce;   // lanes 0-31: nf cols; 32-63: ef cols
      ushort4 o4;
      o4.x = f2bf(vv[0] * inv); o4.y = f2bf(vv[1] * inv);
      o4.z = f2bf(vv[2] * inv); o4.w = f2bf(vv[3] * inv);
      *(ushort4*)&xt[row * LDSR + lane * 4] = o4;
    }
  }
  __syncthreads();

  // ---- GEMM phase (proven node_gemm body, X1 staging replaced by gather) ----
  const int m16 = lane & 15;
  const int quad = lane >> 4;
  const int arow = wid * 16 + m16;
  const int lane8 = lane << 3;

  f32x4 acc[8];
  #pragma unroll
  for (int ot = 0; ot < 8; ++ot) acc[ot] = (f32x4){0.f, 0.f, 0.f, 0.f};

  #pragma unroll
  for (int k0i = 0; k0i < 8; ++k0i) {
    bf16x8 a = *(const bf16x8*)&xt[arow * LDSR + k0i * 32 + quad * 8];
    #pragma unroll
    for (int ot = 0; ot < 8; ++ot) {
      bf16x8 b = *(const bf16x8*)&Wp[((k0i * 8 + ot) << 9) + lane8];
      acc[ot] = __builtin_amdgcn_mfma_f32_16x16x32_bf16(a, b, acc[ot], 0, 0, 0);
    }
  }
  __syncthreads();

  #pragma unroll
  for (int ot = 0; ot < 8; ++ot) {
    int o = ot * 16 + m16;
    float bias = b1[o];
    #pragma unroll
    for (int r = 0; r < 4; ++r) {
      int m = wid * 16 + quad * 4 + r;
      float h = acc[ot][r] + (cnts[m] > 0 ? bias : 0.0f);
      xt[m * LDSR + 128 + o] = f2bf(h);
    }
  }
  #pragma unroll
  for (int it = 0; it < 8; ++it) {
    int chunk = tid + it * 256;
    int r = chunk >> 5, c = chunk & 31;
    int g = base + r;
    float4 v = make_float4(0.f, 0.f, 0.f, 0.f);
    if (g < n_nodes) v = ((const float4*)nfeats)[(size_t)g * 32 + c];
    ushort4 bv;
    bv.x = f2bf(v.x); bv.y = f2bf(v.y); bv.z = f2bf(v.z); bv.w = f2bf(v.w);
    *(ushort4*)&xt[r * LDSR + c * 4] = bv;
  }
  __syncthreads();

  #pragma unroll
  for (int ot = 0; ot < 8; ++ot) acc[ot] = (f32x4){0.f, 0.f, 0.f, 0.f};

  #pragma unroll
  for (int k0i = 0; k0i < 8; ++k0i) {
    bf16x8 a = *(const bf16x8*)&xt[arow * LDSR + k0i * 32 + quad * 8];
    #pragma unroll
    for (int ot = 0; ot < 8; ++ot) {
      bf16x8 b = *(const bf16x8*)&Wp[32768 + ((k0i * 8 + ot) << 9) + lane8];
      acc[ot] = __builtin_amdgcn_mfma_f32_16x16x32_bf16(a, b, acc[ot], 0, 0, 0);
    }
  }
  #pragma unroll
  for (int ot = 0; ot < 8; ++ot) {
    int o = ot * 16 + m16;
    float bias = b2[o];
    #pragma unroll
    for (int r = 0; r < 4; ++r) {
      int m = wid * 16 + quad * 4 + r;
      int g = base + m;
      if (g < n_nodes) {
        float v = acc[ot][r] + bias;
        out[(size_t)g * D + o] = v > 0.f ? v : 0.f;
      }
    }
  }
}

extern "C" void kernel_launch(void* const* d_in, const int* in_sizes, int n_in,
                              void* d_out, int out_size, void* d_ws, size_t ws_size,
                              hipStream_t stream) {
  const float* nfeats = (const float*)d_in[0];
  const float* efeats = (const float*)d_in[1];
  const float* Wmsg_f = (const float*)d_in[2];
  const float* b1     = (const float*)d_in[3];
  const float* Wapp_f = (const float*)d_in[4];
  const float* b2     = (const float*)d_in[5];
  const int*   src    = (const int*)d_in[6];
  const int*   dst    = (const int*)d_in[7];
  const int n_nodes = in_sizes[0] / D;
  const int n_edges = in_sizes[6];
  const int nb = (n_nodes + 1023) / 1024;   // scan blocks (49)

  char* ws = (char*)d_ws;
  size_t off = 0;
  unsigned short* Wp = (unsigned short*)(ws + off); off += (size_t)2 * D * TWO_D * 2;
  int* counts    = (int*)(ws + off); off += (size_t)n_nodes * 4;
  int* offsets   = (int*)(ws + off); off += (size_t)(n_nodes + 1) * 4;
  int* rank      = (int*)(ws + off); off += (size_t)n_edges * 4;
  int* partial   = (int*)(ws + off); off += 64 * 4;
  int2* edge_list = (int2*)(ws + off); off += (size_t)n_edges * 8;
  (void)ws_size; (void)n_in; (void)out_size;

  hipMemsetAsync(counts, 0, (size_t)n_nodes * 4, stream);
  prep_hist<<<(n_edges + 255) / 256, 256, 0, stream>>>(Wmsg_f, Wapp_f, Wp, dst,
                                                       counts, rank, n_edges);
  scan_part<<<nb, 256, 0, stream>>>(counts, partial, n_nodes);
  scan_write<<<nb, 256, 0, stream>>>(counts, partial, offsets, n_nodes, n_edges, nb);
  scatter_kernel<<<(n_edges + 255) / 256, 256, 0, stream>>>(dst, src, rank, offsets,
                                                            edge_list, n_edges);
  gather_gemm<<<(n_nodes + 63) / 64, 256, 0, stream>>>(nfeats, efeats, edge_list,
                                                       offsets, Wp, b1, b2,
                                                       (float*)d_out, n_nodes);
}